// Round 12
// baseline (389.217 us; speedup 1.0000x reference)
//
#include <hip/hip_runtime.h>
#include <cmath>

#define BB 8
#define CC 64
#define HH 128
#define WW 128
#define FH 130          // feath halo dims
#define FW 130

typedef short s8v __attribute__((ext_vector_type(8)));      // raw 16B move
typedef float f4v __attribute__((ext_vector_type(4)));      // 4 fp32 acc
typedef _Float16 h8 __attribute__((ext_vector_type(8)));    // 8 f16 (4 VGPRs)
typedef unsigned short u16;
typedef u16 u4v __attribute__((ext_vector_type(4)));

__device__ __forceinline__ u16 f2h(float f) {
    _Float16 h = (_Float16)f;
    return __builtin_bit_cast(u16, h);
}
__device__ __forceinline__ _Float16 h_from_bits(u16 b) {
    return __builtin_bit_cast(_Float16, b);
}

// ---------------------------------------------------------------------------
// Kernel P (prep): x2nhwc transpose + weight transforms + halo zeroing,
// merged into ONE launch (r8-proven form).
// ---------------------------------------------------------------------------
__global__ __launch_bounds__(256)
void prep_kernel(const float* __restrict__ xvq, const float* __restrict__ xres,
                 u16* __restrict__ xout,
                 const float* __restrict__ W1, const float* __restrict__ Woff,
                 const float* __restrict__ Wmod, const float* __restrict__ Wdcn,
                 u16* __restrict__ W1t, u16* __restrict__ Womt,
                 u16* __restrict__ Wdf, u16* __restrict__ feath)
{
    __shared__ u16 lds[128 * 132];
    const int bid = blockIdx.x;

    if (bid < 1024) {
        const int h = bid & 127;
        const int b = bid >> 7;
        for (int i = 0; i < 16; ++i) {
            const int idx = threadIdx.x + 256 * i;       // 4096 float4
            const int c = idx >> 5;
            const int w4 = (idx & 31) * 4;
            const float* src = (c < 64)
                ? &xvq[(((size_t)b * 64 + c) * HH + h) * WW]
                : &xres[(((size_t)b * 64 + (c - 64)) * HH + h) * WW];
            const float4 v = *(const float4*)(src + w4);
            lds[(w4 + 0) * 132 + c] = f2h(v.x);
            lds[(w4 + 1) * 132 + c] = f2h(v.y);
            lds[(w4 + 2) * 132 + c] = f2h(v.z);
            lds[(w4 + 3) * 132 + c] = f2h(v.w);
        }
        __syncthreads();
        u16* orow = xout + (((size_t)b * HH + h) * WW) * 128;
        for (int i = 0; i < 16; ++i) {
            const int idx = threadIdx.x + 256 * i;       // 4096 ushort4
            const int w = idx >> 5;
            const int q = idx & 31;
            *(u4v*)(orow + (size_t)w * 128 + q * 4) = *(const u4v*)&lds[w * 132 + q * 4];
        }
        return;
    }

    int idx = (bid - 1024) * 256 + threadIdx.x;
    if (idx < 73728) {
        const int ic = idx & 127;
        const int oc = (idx >> 7) & 63;
        const int t  = idx >> 13;
        W1t[idx] = f2h(W1[((size_t)(oc * 128 + ic)) * 9 + t]);
        return;
    }
    idx -= 73728;
    if (idx < 18432) {
        const int c = idx & 63;
        const int o = (idx >> 6) & 31;
        const int t = idx >> 11;
        float v = 0.f;
        if (o < 18)      v = Woff[((size_t)(o * 64 + c)) * 9 + t];
        else if (o < 27) v = Wmod[((size_t)((o - 18) * 64 + c)) * 9 + t];
        Womt[idx] = f2h(v);
        return;
    }
    idx -= 18432;
    if (idx < 36864) {
        const int e = idx & 7;
        const int lane = (idx >> 3) & 63;
        const int frag = idx >> 9;            // 72 = 9*2*2*2
        const int ks = frag & 1;
        const int nt = (frag >> 1) & 1;
        const int wj = (frag >> 2) & 1;
        const int k  = frag >> 3;
        const int lm = lane & 15, kg = lane >> 4;
        const int oc = wj * 32 + nt * 16 + lm;
        const int c  = ks * 32 + kg * 8 + e;
        Wdf[idx] = f2h(Wdcn[((size_t)(oc * 64 + c)) * 9 + k]);
        return;
    }
    idx -= 36864;
    if (idx < 33024) {                        // border zero: 8 b x 516 px x 8 s8v
        const int q  = idx & 7;
        const int px = idx >> 3;
        const int b  = px / 516;
        const int r  = px - b * 516;
        int y, x;
        if (r < 130)      { y = 0;       x = r; }
        else if (r < 260) { y = FH - 1;  x = r - 130; }
        else if (r < 388) { x = 0;       y = r - 259; }
        else              { x = FW - 1;  y = r - 387; }
        *(s8v*)&feath[(((size_t)b * FH + y) * FW + x) * 64 + q * 8] = (s8v)0;
    }
}

// ---------------------------------------------------------------------------
// Kernel A: conv1 implicit-GEMM f16 MFMA (r10 form: 16x8 tile, 1024 blocks,
// tap-group weight staging, LDS 26.8 KB).
// ---------------------------------------------------------------------------
__global__ __launch_bounds__(256)
void conv1_mfma_kernel(const u16* __restrict__ xin, const u16* __restrict__ W1t,
                       const float* __restrict__ b1, u16* __restrict__ feath)
{
    __shared__ u16 sTile[180 * 36];   // [18x10 px][ic32 pad36] 13.0 KB
    __shared__ u16 sW[192 * 36];      // [3taps*64oc][ic32 pad36] 13.8 KB

    const int x0 = blockIdx.x * 16;
    const int y0 = blockIdx.y * 8;
    const int b  = blockIdx.z;
    const int tid = threadIdx.x;
    const int lane = tid & 63;
    const int wave = tid >> 6;
    const int lm = lane & 15;
    const int kg = lane >> 4;

    const u16* xb = xin + ((size_t)b * HH * WW) * 128;

    f4v acc[2][4];
#pragma unroll
    for (int i = 0; i < 2; ++i)
#pragma unroll
        for (int j = 0; j < 4; ++j) acc[i][j] = (f4v)0.f;

    for (int chunk = 0; chunk < 4; ++chunk) {
        const int c0 = chunk * 32;
        __syncthreads();                      // protect prev chunk's reads
        for (int i = 0; i < 3; ++i) {
            const int idx = tid + 256 * i;
            if (idx < 720) {
                const int pix = idx >> 2;
                const int q   = idx & 3;
                const int gy = y0 - 1 + pix / 18;
                const int gx = x0 - 1 + pix % 18;
                s8v v = (s8v)0;
                if ((unsigned)gy < HH && (unsigned)gx < WW)
                    v = *(const s8v*)(xb + ((size_t)(gy * WW + gx)) * 128 + c0 + q * 8);
                *(s8v*)&sTile[pix * 36 + q * 8] = v;
            }
        }
#pragma unroll
        for (int g = 0; g < 3; ++g) {
            if (g > 0) __syncthreads();       // protect prev group's sW reads
            for (int i = 0; i < 3; ++i) {
                const int idx = tid + 256 * i;
                const int row = idx >> 2;     // [0,192): tt*64 + oc
                const int q   = idx & 3;
                *(s8v*)&sW[row * 36 + q * 8] =
                    *(const s8v*)(W1t + (size_t)(g * 192 + row) * 128 + c0 + q * 8);
            }
            __syncthreads();

#pragma unroll
            for (int tt = 0; tt < 3; ++tt) {
                const int t = g * 3 + tt;
                const int dy = t / 3, dx = t % 3;
                h8 a[2], bq[4];
#pragma unroll
                for (int mt = 0; mt < 2; ++mt) {
                    const int p = wave * 32 + mt * 16 + lm;
                    const int sidx = ((p >> 4) + dy) * 18 + (p & 15) + dx;
                    a[mt] = *(const h8*)&sTile[sidx * 36 + kg * 8];
                }
#pragma unroll
                for (int nt = 0; nt < 4; ++nt) {
                    const int oc = nt * 16 + lm;
                    bq[nt] = *(const h8*)&sW[(tt * 64 + oc) * 36 + kg * 8];
                }
#pragma unroll
                for (int mt = 0; mt < 2; ++mt)
#pragma unroll
                    for (int nt = 0; nt < 4; ++nt)
                        acc[mt][nt] = __builtin_amdgcn_mfma_f32_16x16x32_f16(
                            a[mt], bq[nt], acc[mt][nt], 0, 0, 0);
            }
        }
    }

#pragma unroll
    for (int nt = 0; nt < 4; ++nt) {
        const int oc = nt * 16 + lm;
        const float bias = b1[oc];
#pragma unroll
        for (int mt = 0; mt < 2; ++mt)
#pragma unroll
            for (int r = 0; r < 4; ++r) {
                const int p = wave * 32 + mt * 16 + kg * 4 + r;
                const int y = y0 + (p >> 4), x = x0 + (p & 15);
                feath[(((size_t)b * FH + y + 1) * FW + (x + 1)) * 64 + oc] =
                    f2h(acc[mt][nt][r] + bias);
            }
    }
}

// ---------------------------------------------------------------------------
// Kernel B: offset+mod conv -> FINISHED BILINEAR RECORDS (int4, 16B each):
//   { clamped halo base offset, w01 (2 packed f16), w23, 0 }
// GEMM identical to r8; records written coalesced (adjacent px = +16B).
// ---------------------------------------------------------------------------
__global__ __launch_bounds__(256)
void offmod_mfma_kernel(const u16* __restrict__ feath, const u16* __restrict__ Womt,
                        const float* __restrict__ boff, const float* __restrict__ bmod,
                        int* __restrict__ recs)
{
    __shared__ __align__(16) unsigned char sraw[44064];
    u16* sTile = (u16*)sraw;                  // [324][36] 23328 B (phase 1)
    u16* sWom  = (u16*)(sraw + 23328);        // [288][36] 20736 B (phase 1)
    float* sOmT = (float*)sraw;               // [256][29] 29696 B (phase 2 alias)

    const int x0 = blockIdx.x * 16;
    const int y0 = blockIdx.y * 16;
    const int b  = blockIdx.z;
    const int tid = threadIdx.x;
    const int lane = tid & 63;
    const int wave = tid >> 6;
    const int lm = lane & 15;
    const int kg = lane >> 4;

    const u16* fb = feath + ((size_t)b * FH * FW) * 64;

    f4v acc[4][2];
#pragma unroll
    for (int i = 0; i < 4; ++i)
#pragma unroll
        for (int j = 0; j < 2; ++j) acc[i][j] = (f4v)0.f;

    for (int chunk = 0; chunk < 2; ++chunk) {
        const int c0 = chunk * 32;
        __syncthreads();
        for (int i = 0; i < 6; ++i) {
            const int idx = tid + 256 * i;
            if (idx < 1296) {
                const int pix = idx >> 2;
                const int q   = idx & 3;
                const int gy = y0 + pix / 18;
                const int gx = x0 + pix % 18;
                *(s8v*)&sTile[pix * 36 + q * 8] =
                    *(const s8v*)(fb + ((size_t)(gy * FW + gx)) * 64 + c0 + q * 8);
            }
        }
        for (int i = 0; i < 5; ++i) {
            const int idx = tid + 256 * i;
            if (idx < 1152) {
                const int row = idx >> 2;     // t*32 + o
                const int q   = idx & 3;
                *(s8v*)&sWom[row * 36 + q * 8] =
                    *(const s8v*)(Womt + (size_t)row * 64 + c0 + q * 8);
            }
        }
        __syncthreads();

#pragma unroll
        for (int t = 0; t < 9; ++t) {
            const int dy = t / 3, dx = t % 3;
            h8 a[4], bq[2];
#pragma unroll
            for (int mt = 0; mt < 4; ++mt) {
                const int p = wave * 64 + mt * 16 + lm;
                const int sidx = ((p >> 4) + dy) * 18 + (p & 15) + dx;
                a[mt] = *(const h8*)&sTile[sidx * 36 + kg * 8];
            }
#pragma unroll
            for (int nt = 0; nt < 2; ++nt) {
                const int o = nt * 16 + lm;
                bq[nt] = *(const h8*)&sWom[(t * 32 + o) * 36 + kg * 8];
            }
#pragma unroll
            for (int mt = 0; mt < 4; ++mt)
#pragma unroll
                for (int nt = 0; nt < 2; ++nt)
                    acc[mt][nt] = __builtin_amdgcn_mfma_f32_16x16x32_f16(
                        a[mt], bq[nt], acc[mt][nt], 0, 0, 0);
        }
    }

    // ---- phase 2: om values -> LDS (aliased), then build records ----
    __syncthreads();   // all phase-1 LDS reads retired before alias overwrite
#pragma unroll
    for (int nt = 0; nt < 2; ++nt) {
        const int o = nt * 16 + lm;
        if (o < 27) {
#pragma unroll
            for (int mt = 0; mt < 4; ++mt)
#pragma unroll
                for (int r = 0; r < 4; ++r) {
                    const int p = wave * 64 + mt * 16 + kg * 4 + r;
                    const float v = acc[mt][nt][r];
                    sOmT[p * 29 + o] = (o < 18)
                        ? (v + boff[o])
                        : 2.f / (1.f + expf(-(v + bmod[o - 18])));
                }
        }
    }
    __syncthreads();

    {
        const int px = tid;                    // each thread owns one pixel
        const int y = y0 + (px >> 4);
        const int x = x0 + (px & 15);
        const float* omr = &sOmT[px * 29];
#pragma unroll
        for (int k = 0; k < 9; ++k) {
            const float dy  = omr[2 * k];
            const float dxv = omr[2 * k + 1];
            const float m   = omr[18 + k];
            const float pyf = (float)(y + (k / 3) - 1) + dy;
            const float pxf = (float)(x + (k % 3) - 1) + dxv;
            const float fy0 = floorf(pyf), fx0 = floorf(pxf);
            const float wy1 = pyf - fy0, wx1 = pxf - fx0;
            const int iy0 = (int)fy0, ix0 = (int)fx0;
            const float w[4] = { m * (1.f - wy1) * (1.f - wx1), m * (1.f - wy1) * wx1,
                                 m * wy1 * (1.f - wx1),         m * wy1 * wx1 };
            const int ys[4] = { iy0, iy0, iy0 + 1, iy0 + 1 };
            const int xs[4] = { ix0, ix0 + 1, ix0, ix0 + 1 };
            unsigned int wb[4];
#pragma unroll
            for (int cn = 0; cn < 4; ++cn) {
                const bool valid = ((unsigned)ys[cn] < (unsigned)HH) &&
                                   ((unsigned)xs[cn] < (unsigned)WW);
                wb[cn] = (unsigned int)f2h(valid ? w[cn] : 0.f);
            }
            const int cy = min(max(iy0, -1), HH - 1);
            const int cx = min(max(ix0, -1), WW - 1);
            int4 rec;
            rec.x = ((cy + 1) * FW + (cx + 1)) * 64;
            rec.y = (int)(wb[0] | (wb[1] << 16));
            rec.z = (int)(wb[2] | (wb[3] << 16));
            rec.w = 0;
            *(int4*)(recs + ((size_t)((b * 9 + k) * (HH * WW)) + (y * WW + x)) * 4) = rec;
        }
    }
}

// ---------------------------------------------------------------------------
// Kernel C: deformable sampling + modulated einsum, f16 — SLIM, SPILL-SAFE.
// Records prebuilt by offmod; dcn bulk-copies them into a 9.2 KB LDS array
// (one barrier), then runs the r6/r8-proven depth-2 gather pipeline with
// issue() reading one int4 broadcast per (pixel,tap). NO per-thread record
// arrays (r11's scratch-spill bug), no sOm, no record math.
// LDS 27648 B; __launch_bounds__(256,5) -> up to 5 blocks/CU (was 2.4).
// ---------------------------------------------------------------------------
__global__ __launch_bounds__(256, 5)
void dcn_mfma_kernel(const u16* __restrict__ feath, const int* __restrict__ recs,
                     const u16* __restrict__ Wdf, const float* __restrict__ bdcn,
                     float* __restrict__ out)
{
    __shared__ u16 sV[2][64 * 72];    // [buf][p][c64 pad72] 18432 B
    __shared__ int4 sRec[576];        // [k*64+p] 9216 B

    const int b  = blockIdx.z;
    const int x0 = blockIdx.x * 16;
    const int y0 = blockIdx.y * 4;
    const int tid = threadIdx.x;
    const int lane = tid & 63;
    const int wave = tid >> 6;
    const int wi = wave >> 1;
    const int wj = wave & 1;
    const int lm = lane & 15;
    const int kg = lane >> 4;

    // ---- phase 0: bulk-copy this tile's 576 records into LDS ----
    for (int idx = tid; idx < 576; idx += 256) {
        const int p = idx & 63, k = idx >> 6;
        const int y = y0 + (p >> 4), x = x0 + (p & 15);
        sRec[idx] = *(const int4*)(recs +
            ((size_t)((b * 9 + k) * (HH * WW)) + y * WW + x) * 4);
    }
    __syncthreads();

    // gather mapping: thread = (pixel p1, 16-ch group)
    const int p1 = tid >> 2;
    const int cb = (tid & 3) * 16;
    const u16* fb  = feath + ((size_t)b * FH * FW) * 64;
    const u16* wfp = Wdf + (size_t)lane * 8;

    f4v acc[2][2];
#pragma unroll
    for (int i = 0; i < 2; ++i)
#pragma unroll
        for (int j = 0; j < 2; ++j) acc[i][j] = (f4v)0.f;

    // depth-2 pipeline registers: two named gather sets (static, rule #20)
    h8 A0, A1, A2, A3, A4, A5, A6, A7; int wA01, wA23;
    h8 B0, B1, B2, B3, B4, B5, B6, B7; int wB01, wB23;
    h8 bf[2][2][2];                      // [buf][nt][ks] B-frags

    // corners: +0, +64 (x+1), +FW*64 (y+1), +FW*64+64 (u16 units)
    auto issue = [&](int k, h8& r0, h8& r1, h8& r2, h8& r3,
                     h8& r4, h8& r5, h8& r6, h8& r7, int& w01, int& w23) {
        const int4 rc = sRec[k * 64 + p1];   // 4-lane broadcast
        w01 = rc.y; w23 = rc.z;
        const u16* q = fb + rc.x + cb;
        r0 = *(const h8*)(q);
        r1 = *(const h8*)(q + 8);
        r2 = *(const h8*)(q + 64);
        r3 = *(const h8*)(q + 72);
        r4 = *(const h8*)(q + FW * 64);
        r5 = *(const h8*)(q + FW * 64 + 8);
        r6 = *(const h8*)(q + FW * 64 + 64);
        r7 = *(const h8*)(q + FW * 64 + 72);
    };

    auto publish = [&](int buf, int w01, int w23, h8 r0, h8 r1, h8 r2, h8 r3,
                       h8 r4, h8 r5, h8 r6, h8 r7) {
        const h8 w0 = (h8)h_from_bits((u16)((unsigned)w01 & 0xffffu));
        const h8 w1 = (h8)h_from_bits((u16)((unsigned)w01 >> 16));
        const h8 w2 = (h8)h_from_bits((u16)((unsigned)w23 & 0xffffu));
        const h8 w3 = (h8)h_from_bits((u16)((unsigned)w23 >> 16));
        h8 a0 = (h8)(_Float16)0.f, a1 = (h8)(_Float16)0.f;
        a0 += w0 * r0; a1 += w0 * r1;
        a0 += w1 * r2; a1 += w1 * r3;
        a0 += w2 * r4; a1 += w2 * r5;
        a0 += w3 * r6; a1 += w3 * r7;
        *(h8*)&sV[buf][p1 * 72 + cb]     = a0;
        *(h8*)&sV[buf][p1 * 72 + cb + 8] = a1;
    };

    auto loadbf = [&](int k, int buf) {
#pragma unroll
        for (int nt = 0; nt < 2; ++nt)
#pragma unroll
            for (int ks = 0; ks < 2; ++ks)
                bf[buf][nt][ks] = *(const h8*)(wfp +
                    (size_t)((((k * 2 + wj) * 2 + nt) * 2 + ks)) * 512);
    };

    // prologue: g(0)->A, g(1)->B, bf(0), publish(0) from A
    issue(0, A0, A1, A2, A3, A4, A5, A6, A7, wA01, wA23);
    issue(1, B0, B1, B2, B3, B4, B5, B6, B7, wB01, wB23);
    loadbf(0, 0);
    publish(0, wA01, wA23, A0, A1, A2, A3, A4, A5, A6, A7);

#pragma unroll
    for (int k = 0; k < 9; ++k) {
        // issue g(k+2) into the set freed by last iter's publish; no
        // consumption before the barrier -> loads fly across it.
        if (k < 7) {
            if ((k & 1) == 0) issue(k + 2, A0, A1, A2, A3, A4, A5, A6, A7, wA01, wA23);
            else              issue(k + 2, B0, B1, B2, B3, B4, B5, B6, B7, wB01, wB23);
        }
        if (k < 8) loadbf(k + 1, (k & 1) ^ 1);

        // raw barrier: LDS writes retired (lgkmcnt 0); global loads stay
        // in flight (no vmcnt drain).
        __builtin_amdgcn_sched_barrier(0);
        asm volatile("s_waitcnt lgkmcnt(0)" ::: "memory");
        __builtin_amdgcn_s_barrier();
        __builtin_amdgcn_sched_barrier(0);

        // ---- GEMM: acc += V[64p][64c] * Wd[64c][64oc], tap k ----
        h8 a[2][2];
#pragma unroll
        for (int mt = 0; mt < 2; ++mt) {
            const int p = wi * 32 + mt * 16 + lm;
#pragma unroll
            for (int ks = 0; ks < 2; ++ks)
                a[mt][ks] = *(const h8*)&sV[k & 1][p * 72 + ks * 32 + kg * 8];
        }
#pragma unroll
        for (int mt = 0; mt < 2; ++mt)
#pragma unroll
            for (int nt = 0; nt < 2; ++nt)
#pragma unroll
                for (int ks = 0; ks < 2; ++ks)
                    acc[mt][nt] = __builtin_amdgcn_mfma_f32_16x16x32_f16(
                        a[mt][ks], bf[k & 1][nt][ks], acc[mt][nt], 0, 0, 0);

        // publish(k+1) from the set issued a FULL iteration ago, into the
        // other sV buffer.
        if (k < 8) {
            if ((k & 1) == 0)
                publish(1, wB01, wB23, B0, B1, B2, B3, B4, B5, B6, B7);
            else
                publish(0, wA01, wA23, A0, A1, A2, A3, A4, A5, A6, A7);
        }
    }

    // epilogue: NCHW fp32, float4 stores (x0..x0+15 covers full 64B lines)
#pragma unroll
    for (int mt = 0; mt < 2; ++mt)
#pragma unroll
        for (int nt = 0; nt < 2; ++nt) {
            const int oc = wj * 32 + nt * 16 + lm;
            const float bias = bdcn[oc];
            const int pbase = wi * 32 + mt * 16 + kg * 4;
            const int y = y0 + (pbase >> 4);
            const int x = x0 + (pbase & 15);
            float4 v;
            v.x = acc[mt][nt][0] + bias;
            v.y = acc[mt][nt][1] + bias;
            v.z = acc[mt][nt][2] + bias;
            v.w = acc[mt][nt][3] + bias;
            *(float4*)&out[(((size_t)b * CC + oc) * HH + y) * WW + x] = v;
        }
}

extern "C" void kernel_launch(void* const* d_in, const int* in_sizes, int n_in,
                              void* d_out, int out_size, void* d_ws, size_t ws_size,
                              hipStream_t stream)
{
    const float* xvq  = (const float*)d_in[0];
    const float* xres = (const float*)d_in[1];
    const float* W1   = (const float*)d_in[2];
    const float* b1   = (const float*)d_in[3];
    const float* Woff = (const float*)d_in[4];
    const float* boff = (const float*)d_in[5];
    const float* Wmod = (const float*)d_in[6];
    const float* bmod = (const float*)d_in[7];
    const float* Wdcn = (const float*)d_in[8];
    const float* bdcn = (const float*)d_in[9];
    float* out = (float*)d_out;

    u16*  feath = (u16*)d_ws;                              // 8.65M u16 (halo)
    int*  recs  = (int*)(feath + (size_t)BB * FH * FW * 64);   // 4.72M ints (18.9MB)
    u16*  xin   = (u16*)(recs + (size_t)BB * 9 * HH * WW * 4); // 16.78M u16
    u16*  W1t   = xin + (size_t)BB * HH * WW * 128;        // 73728 u16
    u16*  Womt  = W1t + 9 * 64 * 128;                      // 18432 u16
    u16*  Wdf   = Womt + 9 * 32 * 64;                      // 36864 u16

    prep_kernel<<<dim3(1024 + 633), 256, 0, stream>>>(
        xvq, xres, xin, W1, Woff, Wmod, Wdcn, W1t, Womt, Wdf, feath);
    conv1_mfma_kernel<<<dim3(8, 16, 8), 256, 0, stream>>>(xin, W1t, b1, feath);
    offmod_mfma_kernel<<<dim3(8, 8, 8), 256, 0, stream>>>(feath, Womt, boff, bmod, recs);
    dcn_mfma_kernel<<<dim3(8, 32, 8), 256, 0, stream>>>(feath, recs, Wdf, bdcn, out);
}

// Round 13
// 217.454 us; speedup vs baseline: 1.7899x; 1.7899x over previous
//
#include <hip/hip_runtime.h>
#include <cmath>

#define BB 8
#define CC 64
#define HH 128
#define WW 128
#define FH 130          // feath halo dims
#define FW 130

typedef short s8v __attribute__((ext_vector_type(8)));      // raw 16B move
typedef float f4v __attribute__((ext_vector_type(4)));      // 4 fp32 acc
typedef _Float16 h8 __attribute__((ext_vector_type(8)));    // 8 f16 (4 VGPRs)
typedef unsigned short u16;
typedef u16 u4v __attribute__((ext_vector_type(4)));

__device__ __forceinline__ u16 f2h(float f) {
    _Float16 h = (_Float16)f;
    return __builtin_bit_cast(u16, h);
}
__device__ __forceinline__ _Float16 h_from_bits(u16 b) {
    return __builtin_bit_cast(_Float16, b);
}

// ---------------------------------------------------------------------------
// Kernel P (prep): x2nhwc transpose + weight transforms + halo zeroing,
// merged into ONE launch (r8-proven form).
// ---------------------------------------------------------------------------
__global__ __launch_bounds__(256)
void prep_kernel(const float* __restrict__ xvq, const float* __restrict__ xres,
                 u16* __restrict__ xout,
                 const float* __restrict__ W1, const float* __restrict__ Woff,
                 const float* __restrict__ Wmod, const float* __restrict__ Wdcn,
                 u16* __restrict__ W1t, u16* __restrict__ Womt,
                 u16* __restrict__ Wdf, u16* __restrict__ feath)
{
    __shared__ u16 lds[128 * 132];
    const int bid = blockIdx.x;

    if (bid < 1024) {
        const int h = bid & 127;
        const int b = bid >> 7;
        for (int i = 0; i < 16; ++i) {
            const int idx = threadIdx.x + 256 * i;       // 4096 float4
            const int c = idx >> 5;
            const int w4 = (idx & 31) * 4;
            const float* src = (c < 64)
                ? &xvq[(((size_t)b * 64 + c) * HH + h) * WW]
                : &xres[(((size_t)b * 64 + (c - 64)) * HH + h) * WW];
            const float4 v = *(const float4*)(src + w4);
            lds[(w4 + 0) * 132 + c] = f2h(v.x);
            lds[(w4 + 1) * 132 + c] = f2h(v.y);
            lds[(w4 + 2) * 132 + c] = f2h(v.z);
            lds[(w4 + 3) * 132 + c] = f2h(v.w);
        }
        __syncthreads();
        u16* orow = xout + (((size_t)b * HH + h) * WW) * 128;
        for (int i = 0; i < 16; ++i) {
            const int idx = threadIdx.x + 256 * i;       // 4096 ushort4
            const int w = idx >> 5;
            const int q = idx & 31;
            *(u4v*)(orow + (size_t)w * 128 + q * 4) = *(const u4v*)&lds[w * 132 + q * 4];
        }
        return;
    }

    int idx = (bid - 1024) * 256 + threadIdx.x;
    if (idx < 73728) {
        const int ic = idx & 127;
        const int oc = (idx >> 7) & 63;
        const int t  = idx >> 13;
        W1t[idx] = f2h(W1[((size_t)(oc * 128 + ic)) * 9 + t]);
        return;
    }
    idx -= 73728;
    if (idx < 18432) {
        const int c = idx & 63;
        const int o = (idx >> 6) & 31;
        const int t = idx >> 11;
        float v = 0.f;
        if (o < 18)      v = Woff[((size_t)(o * 64 + c)) * 9 + t];
        else if (o < 27) v = Wmod[((size_t)((o - 18) * 64 + c)) * 9 + t];
        Womt[idx] = f2h(v);
        return;
    }
    idx -= 18432;
    if (idx < 36864) {
        const int e = idx & 7;
        const int lane = (idx >> 3) & 63;
        const int frag = idx >> 9;            // 72 = 9*2*2*2
        const int ks = frag & 1;
        const int nt = (frag >> 1) & 1;
        const int wj = (frag >> 2) & 1;
        const int k  = frag >> 3;
        const int lm = lane & 15, kg = lane >> 4;
        const int oc = wj * 32 + nt * 16 + lm;
        const int c  = ks * 32 + kg * 8 + e;
        Wdf[idx] = f2h(Wdcn[((size_t)(oc * 64 + c)) * 9 + k]);
        return;
    }
    idx -= 36864;
    if (idx < 33024) {                        // border zero: 8 b x 516 px x 8 s8v
        const int q  = idx & 7;
        const int px = idx >> 3;
        const int b  = px / 516;
        const int r  = px - b * 516;
        int y, x;
        if (r < 130)      { y = 0;       x = r; }
        else if (r < 260) { y = FH - 1;  x = r - 130; }
        else if (r < 388) { x = 0;       y = r - 259; }
        else              { x = FW - 1;  y = r - 387; }
        *(s8v*)&feath[(((size_t)b * FH + y) * FW + x) * 64 + q * 8] = (s8v)0;
    }
}

// ---------------------------------------------------------------------------
// Kernel A: conv1 implicit-GEMM f16 MFMA (r10 form: 16x8 tile, 1024 blocks,
// tap-group weight staging, LDS 26.8 KB).
// ---------------------------------------------------------------------------
__global__ __launch_bounds__(256)
void conv1_mfma_kernel(const u16* __restrict__ xin, const u16* __restrict__ W1t,
                       const float* __restrict__ b1, u16* __restrict__ feath)
{
    __shared__ u16 sTile[180 * 36];   // [18x10 px][ic32 pad36] 13.0 KB
    __shared__ u16 sW[192 * 36];      // [3taps*64oc][ic32 pad36] 13.8 KB

    const int x0 = blockIdx.x * 16;
    const int y0 = blockIdx.y * 8;
    const int b  = blockIdx.z;
    const int tid = threadIdx.x;
    const int lane = tid & 63;
    const int wave = tid >> 6;
    const int lm = lane & 15;
    const int kg = lane >> 4;

    const u16* xb = xin + ((size_t)b * HH * WW) * 128;

    f4v acc[2][4];
#pragma unroll
    for (int i = 0; i < 2; ++i)
#pragma unroll
        for (int j = 0; j < 4; ++j) acc[i][j] = (f4v)0.f;

    for (int chunk = 0; chunk < 4; ++chunk) {
        const int c0 = chunk * 32;
        __syncthreads();                      // protect prev chunk's reads
        for (int i = 0; i < 3; ++i) {
            const int idx = tid + 256 * i;
            if (idx < 720) {
                const int pix = idx >> 2;
                const int q   = idx & 3;
                const int gy = y0 - 1 + pix / 18;
                const int gx = x0 - 1 + pix % 18;
                s8v v = (s8v)0;
                if ((unsigned)gy < HH && (unsigned)gx < WW)
                    v = *(const s8v*)(xb + ((size_t)(gy * WW + gx)) * 128 + c0 + q * 8);
                *(s8v*)&sTile[pix * 36 + q * 8] = v;
            }
        }
#pragma unroll
        for (int g = 0; g < 3; ++g) {
            if (g > 0) __syncthreads();       // protect prev group's sW reads
            for (int i = 0; i < 3; ++i) {
                const int idx = tid + 256 * i;
                const int row = idx >> 2;     // [0,192): tt*64 + oc
                const int q   = idx & 3;
                *(s8v*)&sW[row * 36 + q * 8] =
                    *(const s8v*)(W1t + (size_t)(g * 192 + row) * 128 + c0 + q * 8);
            }
            __syncthreads();

#pragma unroll
            for (int tt = 0; tt < 3; ++tt) {
                const int t = g * 3 + tt;
                const int dy = t / 3, dx = t % 3;
                h8 a[2], bq[4];
#pragma unroll
                for (int mt = 0; mt < 2; ++mt) {
                    const int p = wave * 32 + mt * 16 + lm;
                    const int sidx = ((p >> 4) + dy) * 18 + (p & 15) + dx;
                    a[mt] = *(const h8*)&sTile[sidx * 36 + kg * 8];
                }
#pragma unroll
                for (int nt = 0; nt < 4; ++nt) {
                    const int oc = nt * 16 + lm;
                    bq[nt] = *(const h8*)&sW[(tt * 64 + oc) * 36 + kg * 8];
                }
#pragma unroll
                for (int mt = 0; mt < 2; ++mt)
#pragma unroll
                    for (int nt = 0; nt < 4; ++nt)
                        acc[mt][nt] = __builtin_amdgcn_mfma_f32_16x16x32_f16(
                            a[mt], bq[nt], acc[mt][nt], 0, 0, 0);
            }
        }
    }

#pragma unroll
    for (int nt = 0; nt < 4; ++nt) {
        const int oc = nt * 16 + lm;
        const float bias = b1[oc];
#pragma unroll
        for (int mt = 0; mt < 2; ++mt)
#pragma unroll
            for (int r = 0; r < 4; ++r) {
                const int p = wave * 32 + mt * 16 + kg * 4 + r;
                const int y = y0 + (p >> 4), x = x0 + (p & 15);
                feath[(((size_t)b * FH + y + 1) * FW + (x + 1)) * 64 + oc] =
                    f2h(acc[mt][nt][r] + bias);
            }
    }
}

// ---------------------------------------------------------------------------
// Kernel B: offset+mod conv -> FINISHED BILINEAR RECORDS (int4, 16B each):
//   { clamped halo base offset, w01 (2 packed f16), w23, 0 }
// GEMM identical to r8; records written coalesced (adjacent px = +16B).
// ---------------------------------------------------------------------------
__global__ __launch_bounds__(256)
void offmod_mfma_kernel(const u16* __restrict__ feath, const u16* __restrict__ Womt,
                        const float* __restrict__ boff, const float* __restrict__ bmod,
                        int* __restrict__ recs)
{
    __shared__ __align__(16) unsigned char sraw[44064];
    u16* sTile = (u16*)sraw;                  // [324][36] 23328 B (phase 1)
    u16* sWom  = (u16*)(sraw + 23328);        // [288][36] 20736 B (phase 1)
    float* sOmT = (float*)sraw;               // [256][29] 29696 B (phase 2 alias)

    const int x0 = blockIdx.x * 16;
    const int y0 = blockIdx.y * 16;
    const int b  = blockIdx.z;
    const int tid = threadIdx.x;
    const int lane = tid & 63;
    const int wave = tid >> 6;
    const int lm = lane & 15;
    const int kg = lane >> 4;

    const u16* fb = feath + ((size_t)b * FH * FW) * 64;

    f4v acc[4][2];
#pragma unroll
    for (int i = 0; i < 4; ++i)
#pragma unroll
        for (int j = 0; j < 2; ++j) acc[i][j] = (f4v)0.f;

    for (int chunk = 0; chunk < 2; ++chunk) {
        const int c0 = chunk * 32;
        __syncthreads();
        for (int i = 0; i < 6; ++i) {
            const int idx = tid + 256 * i;
            if (idx < 1296) {
                const int pix = idx >> 2;
                const int q   = idx & 3;
                const int gy = y0 + pix / 18;
                const int gx = x0 + pix % 18;
                *(s8v*)&sTile[pix * 36 + q * 8] =
                    *(const s8v*)(fb + ((size_t)(gy * FW + gx)) * 64 + c0 + q * 8);
            }
        }
        for (int i = 0; i < 5; ++i) {
            const int idx = tid + 256 * i;
            if (idx < 1152) {
                const int row = idx >> 2;     // t*32 + o
                const int q   = idx & 3;
                *(s8v*)&sWom[row * 36 + q * 8] =
                    *(const s8v*)(Womt + (size_t)row * 64 + c0 + q * 8);
            }
        }
        __syncthreads();

#pragma unroll
        for (int t = 0; t < 9; ++t) {
            const int dy = t / 3, dx = t % 3;
            h8 a[4], bq[2];
#pragma unroll
            for (int mt = 0; mt < 4; ++mt) {
                const int p = wave * 64 + mt * 16 + lm;
                const int sidx = ((p >> 4) + dy) * 18 + (p & 15) + dx;
                a[mt] = *(const h8*)&sTile[sidx * 36 + kg * 8];
            }
#pragma unroll
            for (int nt = 0; nt < 2; ++nt) {
                const int o = nt * 16 + lm;
                bq[nt] = *(const h8*)&sWom[(t * 32 + o) * 36 + kg * 8];
            }
#pragma unroll
            for (int mt = 0; mt < 4; ++mt)
#pragma unroll
                for (int nt = 0; nt < 2; ++nt)
                    acc[mt][nt] = __builtin_amdgcn_mfma_f32_16x16x32_f16(
                        a[mt], bq[nt], acc[mt][nt], 0, 0, 0);
        }
    }

    // ---- phase 2: om values -> LDS (aliased), then build records ----
    __syncthreads();   // all phase-1 LDS reads retired before alias overwrite
#pragma unroll
    for (int nt = 0; nt < 2; ++nt) {
        const int o = nt * 16 + lm;
        if (o < 27) {
#pragma unroll
            for (int mt = 0; mt < 4; ++mt)
#pragma unroll
                for (int r = 0; r < 4; ++r) {
                    const int p = wave * 64 + mt * 16 + kg * 4 + r;
                    const float v = acc[mt][nt][r];
                    sOmT[p * 29 + o] = (o < 18)
                        ? (v + boff[o])
                        : 2.f / (1.f + expf(-(v + bmod[o - 18])));
                }
        }
    }
    __syncthreads();

    {
        const int px = tid;                    // each thread owns one pixel
        const int y = y0 + (px >> 4);
        const int x = x0 + (px & 15);
        const float* omr = &sOmT[px * 29];
#pragma unroll
        for (int k = 0; k < 9; ++k) {
            const float dy  = omr[2 * k];
            const float dxv = omr[2 * k + 1];
            const float m   = omr[18 + k];
            const float pyf = (float)(y + (k / 3) - 1) + dy;
            const float pxf = (float)(x + (k % 3) - 1) + dxv;
            const float fy0 = floorf(pyf), fx0 = floorf(pxf);
            const float wy1 = pyf - fy0, wx1 = pxf - fx0;
            const int iy0 = (int)fy0, ix0 = (int)fx0;
            const float w[4] = { m * (1.f - wy1) * (1.f - wx1), m * (1.f - wy1) * wx1,
                                 m * wy1 * (1.f - wx1),         m * wy1 * wx1 };
            const int ys[4] = { iy0, iy0, iy0 + 1, iy0 + 1 };
            const int xs[4] = { ix0, ix0 + 1, ix0, ix0 + 1 };
            unsigned int wb[4];
#pragma unroll
            for (int cn = 0; cn < 4; ++cn) {
                const bool valid = ((unsigned)ys[cn] < (unsigned)HH) &&
                                   ((unsigned)xs[cn] < (unsigned)WW);
                wb[cn] = (unsigned int)f2h(valid ? w[cn] : 0.f);
            }
            const int cy = min(max(iy0, -1), HH - 1);
            const int cx = min(max(ix0, -1), WW - 1);
            int4 rec;
            rec.x = ((cy + 1) * FW + (cx + 1)) * 64;
            rec.y = (int)(wb[0] | (wb[1] << 16));
            rec.z = (int)(wb[2] | (wb[3] << 16));
            rec.w = 0;
            *(int4*)(recs + ((size_t)((b * 9 + k) * (HH * WW)) + (y * WW + x)) * 4) = rec;
        }
    }
}

// ---------------------------------------------------------------------------
// Kernel C: deformable sampling + modulated einsum, f16 — SLIM, SPILL-SAFE.
// r12 structure (records via LDS bulk-copy, no per-thread arrays) with the
// REGISTER-CAP FIX: __launch_bounds__(256, 3). r11/r12 both spilled because
// min-waves 4/5 capped VGPR below the depth-2 pipeline's ~100 natural use
// (measured: VGPR_Count 64/48, WRITE 381/612 MB scratch). At 3 waves/EU the
// cap is ~170; r8's identical pipeline allocated 84 with zero spill.
// LDS 27648 B (vs r8's 39424) -> 5 blocks/CU LDS-capable.
// ---------------------------------------------------------------------------
__global__ __launch_bounds__(256, 3)
void dcn_mfma_kernel(const u16* __restrict__ feath, const int* __restrict__ recs,
                     const u16* __restrict__ Wdf, const float* __restrict__ bdcn,
                     float* __restrict__ out)
{
    __shared__ u16 sV[2][64 * 72];    // [buf][p][c64 pad72] 18432 B
    __shared__ int4 sRec[576];        // [k*64+p] 9216 B

    const int b  = blockIdx.z;
    const int x0 = blockIdx.x * 16;
    const int y0 = blockIdx.y * 4;
    const int tid = threadIdx.x;
    const int lane = tid & 63;
    const int wave = tid >> 6;
    const int wi = wave >> 1;
    const int wj = wave & 1;
    const int lm = lane & 15;
    const int kg = lane >> 4;

    // ---- phase 0: bulk-copy this tile's 576 records into LDS ----
    for (int idx = tid; idx < 576; idx += 256) {
        const int p = idx & 63, k = idx >> 6;
        const int y = y0 + (p >> 4), x = x0 + (p & 15);
        sRec[idx] = *(const int4*)(recs +
            ((size_t)((b * 9 + k) * (HH * WW)) + y * WW + x) * 4);
    }
    __syncthreads();

    // gather mapping: thread = (pixel p1, 16-ch group)
    const int p1 = tid >> 2;
    const int cb = (tid & 3) * 16;
    const u16* fb  = feath + ((size_t)b * FH * FW) * 64;
    const u16* wfp = Wdf + (size_t)lane * 8;

    f4v acc[2][2];
#pragma unroll
    for (int i = 0; i < 2; ++i)
#pragma unroll
        for (int j = 0; j < 2; ++j) acc[i][j] = (f4v)0.f;

    // depth-2 pipeline registers: two named gather sets (static, rule #20)
    h8 A0, A1, A2, A3, A4, A5, A6, A7; int wA01, wA23;
    h8 B0, B1, B2, B3, B4, B5, B6, B7; int wB01, wB23;
    h8 bf[2][2][2];                      // [buf][nt][ks] B-frags

    // corners: +0, +64 (x+1), +FW*64 (y+1), +FW*64+64 (u16 units)
    auto issue = [&](int k, h8& r0, h8& r1, h8& r2, h8& r3,
                     h8& r4, h8& r5, h8& r6, h8& r7, int& w01, int& w23) {
        const int4 rc = sRec[k * 64 + p1];   // 4-lane broadcast
        w01 = rc.y; w23 = rc.z;
        const u16* q = fb + rc.x + cb;
        r0 = *(const h8*)(q);
        r1 = *(const h8*)(q + 8);
        r2 = *(const h8*)(q + 64);
        r3 = *(const h8*)(q + 72);
        r4 = *(const h8*)(q + FW * 64);
        r5 = *(const h8*)(q + FW * 64 + 8);
        r6 = *(const h8*)(q + FW * 64 + 64);
        r7 = *(const h8*)(q + FW * 64 + 72);
    };

    auto publish = [&](int buf, int w01, int w23, h8 r0, h8 r1, h8 r2, h8 r3,
                       h8 r4, h8 r5, h8 r6, h8 r7) {
        const h8 w0 = (h8)h_from_bits((u16)((unsigned)w01 & 0xffffu));
        const h8 w1 = (h8)h_from_bits((u16)((unsigned)w01 >> 16));
        const h8 w2 = (h8)h_from_bits((u16)((unsigned)w23 & 0xffffu));
        const h8 w3 = (h8)h_from_bits((u16)((unsigned)w23 >> 16));
        h8 a0 = (h8)(_Float16)0.f, a1 = (h8)(_Float16)0.f;
        a0 += w0 * r0; a1 += w0 * r1;
        a0 += w1 * r2; a1 += w1 * r3;
        a0 += w2 * r4; a1 += w2 * r5;
        a0 += w3 * r6; a1 += w3 * r7;
        *(h8*)&sV[buf][p1 * 72 + cb]     = a0;
        *(h8*)&sV[buf][p1 * 72 + cb + 8] = a1;
    };

    auto loadbf = [&](int k, int buf) {
#pragma unroll
        for (int nt = 0; nt < 2; ++nt)
#pragma unroll
            for (int ks = 0; ks < 2; ++ks)
                bf[buf][nt][ks] = *(const h8*)(wfp +
                    (size_t)((((k * 2 + wj) * 2 + nt) * 2 + ks)) * 512);
    };

    // prologue: g(0)->A, g(1)->B, bf(0), publish(0) from A
    issue(0, A0, A1, A2, A3, A4, A5, A6, A7, wA01, wA23);
    issue(1, B0, B1, B2, B3, B4, B5, B6, B7, wB01, wB23);
    loadbf(0, 0);
    publish(0, wA01, wA23, A0, A1, A2, A3, A4, A5, A6, A7);

#pragma unroll
    for (int k = 0; k < 9; ++k) {
        // issue g(k+2) into the set freed by last iter's publish; no
        // consumption before the barrier -> loads fly across it.
        if (k < 7) {
            if ((k & 1) == 0) issue(k + 2, A0, A1, A2, A3, A4, A5, A6, A7, wA01, wA23);
            else              issue(k + 2, B0, B1, B2, B3, B4, B5, B6, B7, wB01, wB23);
        }
        if (k < 8) loadbf(k + 1, (k & 1) ^ 1);

        // raw barrier: LDS writes retired (lgkmcnt 0); global loads stay
        // in flight (no vmcnt drain).
        __builtin_amdgcn_sched_barrier(0);
        asm volatile("s_waitcnt lgkmcnt(0)" ::: "memory");
        __builtin_amdgcn_s_barrier();
        __builtin_amdgcn_sched_barrier(0);

        // ---- GEMM: acc += V[64p][64c] * Wd[64c][64oc], tap k ----
        h8 a[2][2];
#pragma unroll
        for (int mt = 0; mt < 2; ++mt) {
            const int p = wi * 32 + mt * 16 + lm;
#pragma unroll
            for (int ks = 0; ks < 2; ++ks)
                a[mt][ks] = *(const h8*)&sV[k & 1][p * 72 + ks * 32 + kg * 8];
        }
#pragma unroll
        for (int mt = 0; mt < 2; ++mt)
#pragma unroll
            for (int nt = 0; nt < 2; ++nt)
#pragma unroll
                for (int ks = 0; ks < 2; ++ks)
                    acc[mt][nt] = __builtin_amdgcn_mfma_f32_16x16x32_f16(
                        a[mt][ks], bf[k & 1][nt][ks], acc[mt][nt], 0, 0, 0);

        // publish(k+1) from the set issued a FULL iteration ago, into the
        // other sV buffer.
        if (k < 8) {
            if ((k & 1) == 0)
                publish(1, wB01, wB23, B0, B1, B2, B3, B4, B5, B6, B7);
            else
                publish(0, wA01, wA23, A0, A1, A2, A3, A4, A5, A6, A7);
        }
    }

    // epilogue: NCHW fp32, float4 stores (x0..x0+15 covers full 64B lines)
#pragma unroll
    for (int mt = 0; mt < 2; ++mt)
#pragma unroll
        for (int nt = 0; nt < 2; ++nt) {
            const int oc = wj * 32 + nt * 16 + lm;
            const float bias = bdcn[oc];
            const int pbase = wi * 32 + mt * 16 + kg * 4;
            const int y = y0 + (pbase >> 4);
            const int x = x0 + (pbase & 15);
            float4 v;
            v.x = acc[mt][nt][0] + bias;
            v.y = acc[mt][nt][1] + bias;
            v.z = acc[mt][nt][2] + bias;
            v.w = acc[mt][nt][3] + bias;
            *(float4*)&out[(((size_t)b * CC + oc) * HH + y) * WW + x] = v;
        }
}

extern "C" void kernel_launch(void* const* d_in, const int* in_sizes, int n_in,
                              void* d_out, int out_size, void* d_ws, size_t ws_size,
                              hipStream_t stream)
{
    const float* xvq  = (const float*)d_in[0];
    const float* xres = (const float*)d_in[1];
    const float* W1   = (const float*)d_in[2];
    const float* b1   = (const float*)d_in[3];
    const float* Woff = (const float*)d_in[4];
    const float* boff = (const float*)d_in[5];
    const float* Wmod = (const float*)d_in[6];
    const float* bmod = (const float*)d_in[7];
    const float* Wdcn = (const float*)d_in[8];
    const float* bdcn = (const float*)d_in[9];
    float* out = (float*)d_out;

    u16*  feath = (u16*)d_ws;                              // 8.65M u16 (halo)
    int*  recs  = (int*)(feath + (size_t)BB * FH * FW * 64);   // 4.72M ints (18.9MB)
    u16*  xin   = (u16*)(recs + (size_t)BB * 9 * HH * WW * 4); // 16.78M u16
    u16*  W1t   = xin + (size_t)BB * HH * WW * 128;        // 73728 u16
    u16*  Womt  = W1t + 9 * 64 * 128;                      // 18432 u16
    u16*  Wdf   = Womt + 9 * 32 * 64;                      // 36864 u16

    prep_kernel<<<dim3(1024 + 633), 256, 0, stream>>>(
        xvq, xres, xin, W1, Woff, Wmod, Wdcn, W1t, Womt, Wdf, feath);
    conv1_mfma_kernel<<<dim3(8, 16, 8), 256, 0, stream>>>(xin, W1t, b1, feath);
    offmod_mfma_kernel<<<dim3(8, 8, 8), 256, 0, stream>>>(feath, Womt, boff, bmod, recs);
    dcn_mfma_kernel<<<dim3(8, 32, 8), 256, 0, stream>>>(feath, recs, Wdf, bdcn, out);
}

// Round 14
// 208.640 us; speedup vs baseline: 1.8655x; 1.0422x over previous
//
#include <hip/hip_runtime.h>
#include <cmath>

#define BB 8
#define CC 64
#define HH 128
#define WW 128
#define FH 130          // feath halo dims
#define FW 130

typedef short s8v __attribute__((ext_vector_type(8)));      // raw 16B move
typedef float f4v __attribute__((ext_vector_type(4)));      // 4 fp32 acc
typedef _Float16 h8 __attribute__((ext_vector_type(8)));    // 8 f16 (4 VGPRs)
typedef unsigned short u16;
typedef u16 u4v __attribute__((ext_vector_type(4)));

__device__ __forceinline__ u16 f2h(float f) {
    _Float16 h = (_Float16)f;
    return __builtin_bit_cast(u16, h);
}
__device__ __forceinline__ _Float16 h_from_bits(u16 b) {
    return __builtin_bit_cast(_Float16, b);
}

// ---------------------------------------------------------------------------
// Kernel P (prep): x2nhwc transpose + weight transforms + halo zeroing,
// merged into ONE launch (r8-proven form).
// ---------------------------------------------------------------------------
__global__ __launch_bounds__(256)
void prep_kernel(const float* __restrict__ xvq, const float* __restrict__ xres,
                 u16* __restrict__ xout,
                 const float* __restrict__ W1, const float* __restrict__ Woff,
                 const float* __restrict__ Wmod, const float* __restrict__ Wdcn,
                 u16* __restrict__ W1t, u16* __restrict__ Womt,
                 u16* __restrict__ Wdf, u16* __restrict__ feath)
{
    __shared__ u16 lds[128 * 132];
    const int bid = blockIdx.x;

    if (bid < 1024) {
        const int h = bid & 127;
        const int b = bid >> 7;
        for (int i = 0; i < 16; ++i) {
            const int idx = threadIdx.x + 256 * i;       // 4096 float4
            const int c = idx >> 5;
            const int w4 = (idx & 31) * 4;
            const float* src = (c < 64)
                ? &xvq[(((size_t)b * 64 + c) * HH + h) * WW]
                : &xres[(((size_t)b * 64 + (c - 64)) * HH + h) * WW];
            const float4 v = *(const float4*)(src + w4);
            lds[(w4 + 0) * 132 + c] = f2h(v.x);
            lds[(w4 + 1) * 132 + c] = f2h(v.y);
            lds[(w4 + 2) * 132 + c] = f2h(v.z);
            lds[(w4 + 3) * 132 + c] = f2h(v.w);
        }
        __syncthreads();
        u16* orow = xout + (((size_t)b * HH + h) * WW) * 128;
        for (int i = 0; i < 16; ++i) {
            const int idx = threadIdx.x + 256 * i;       // 4096 ushort4
            const int w = idx >> 5;
            const int q = idx & 31;
            *(u4v*)(orow + (size_t)w * 128 + q * 4) = *(const u4v*)&lds[w * 132 + q * 4];
        }
        return;
    }

    int idx = (bid - 1024) * 256 + threadIdx.x;
    if (idx < 73728) {
        const int ic = idx & 127;
        const int oc = (idx >> 7) & 63;
        const int t  = idx >> 13;
        W1t[idx] = f2h(W1[((size_t)(oc * 128 + ic)) * 9 + t]);
        return;
    }
    idx -= 73728;
    if (idx < 18432) {
        const int c = idx & 63;
        const int o = (idx >> 6) & 31;
        const int t = idx >> 11;
        float v = 0.f;
        if (o < 18)      v = Woff[((size_t)(o * 64 + c)) * 9 + t];
        else if (o < 27) v = Wmod[((size_t)((o - 18) * 64 + c)) * 9 + t];
        Womt[idx] = f2h(v);
        return;
    }
    idx -= 18432;
    if (idx < 36864) {
        const int e = idx & 7;
        const int lane = (idx >> 3) & 63;
        const int frag = idx >> 9;            // 72 = 9*2*2*2
        const int ks = frag & 1;
        const int nt = (frag >> 1) & 1;
        const int wj = (frag >> 2) & 1;
        const int k  = frag >> 3;
        const int lm = lane & 15, kg = lane >> 4;
        const int oc = wj * 32 + nt * 16 + lm;
        const int c  = ks * 32 + kg * 8 + e;
        Wdf[idx] = f2h(Wdcn[((size_t)(oc * 64 + c)) * 9 + k]);
        return;
    }
    idx -= 36864;
    if (idx < 33024) {                        // border zero: 8 b x 516 px x 8 s8v
        const int q  = idx & 7;
        const int px = idx >> 3;
        const int b  = px / 516;
        const int r  = px - b * 516;
        int y, x;
        if (r < 130)      { y = 0;       x = r; }
        else if (r < 260) { y = FH - 1;  x = r - 130; }
        else if (r < 388) { x = 0;       y = r - 259; }
        else              { x = FW - 1;  y = r - 387; }
        *(s8v*)&feath[(((size_t)b * FH + y) * FW + x) * 64 + q * 8] = (s8v)0;
    }
}

// ---------------------------------------------------------------------------
// Kernel A: conv1 implicit-GEMM f16 MFMA (r10 form: 16x8 tile, 1024 blocks,
// tap-group weight staging, LDS 26.8 KB).
// ---------------------------------------------------------------------------
__global__ __launch_bounds__(256)
void conv1_mfma_kernel(const u16* __restrict__ xin, const u16* __restrict__ W1t,
                       const float* __restrict__ b1, u16* __restrict__ feath)
{
    __shared__ u16 sTile[180 * 36];   // [18x10 px][ic32 pad36] 13.0 KB
    __shared__ u16 sW[192 * 36];      // [3taps*64oc][ic32 pad36] 13.8 KB

    const int x0 = blockIdx.x * 16;
    const int y0 = blockIdx.y * 8;
    const int b  = blockIdx.z;
    const int tid = threadIdx.x;
    const int lane = tid & 63;
    const int wave = tid >> 6;
    const int lm = lane & 15;
    const int kg = lane >> 4;

    const u16* xb = xin + ((size_t)b * HH * WW) * 128;

    f4v acc[2][4];
#pragma unroll
    for (int i = 0; i < 2; ++i)
#pragma unroll
        for (int j = 0; j < 4; ++j) acc[i][j] = (f4v)0.f;

    for (int chunk = 0; chunk < 4; ++chunk) {
        const int c0 = chunk * 32;
        __syncthreads();                      // protect prev chunk's reads
        for (int i = 0; i < 3; ++i) {
            const int idx = tid + 256 * i;
            if (idx < 720) {
                const int pix = idx >> 2;
                const int q   = idx & 3;
                const int gy = y0 - 1 + pix / 18;
                const int gx = x0 - 1 + pix % 18;
                s8v v = (s8v)0;
                if ((unsigned)gy < HH && (unsigned)gx < WW)
                    v = *(const s8v*)(xb + ((size_t)(gy * WW + gx)) * 128 + c0 + q * 8);
                *(s8v*)&sTile[pix * 36 + q * 8] = v;
            }
        }
#pragma unroll
        for (int g = 0; g < 3; ++g) {
            if (g > 0) __syncthreads();       // protect prev group's sW reads
            for (int i = 0; i < 3; ++i) {
                const int idx = tid + 256 * i;
                const int row = idx >> 2;     // [0,192): tt*64 + oc
                const int q   = idx & 3;
                *(s8v*)&sW[row * 36 + q * 8] =
                    *(const s8v*)(W1t + (size_t)(g * 192 + row) * 128 + c0 + q * 8);
            }
            __syncthreads();

#pragma unroll
            for (int tt = 0; tt < 3; ++tt) {
                const int t = g * 3 + tt;
                const int dy = t / 3, dx = t % 3;
                h8 a[2], bq[4];
#pragma unroll
                for (int mt = 0; mt < 2; ++mt) {
                    const int p = wave * 32 + mt * 16 + lm;
                    const int sidx = ((p >> 4) + dy) * 18 + (p & 15) + dx;
                    a[mt] = *(const h8*)&sTile[sidx * 36 + kg * 8];
                }
#pragma unroll
                for (int nt = 0; nt < 4; ++nt) {
                    const int oc = nt * 16 + lm;
                    bq[nt] = *(const h8*)&sW[(tt * 64 + oc) * 36 + kg * 8];
                }
#pragma unroll
                for (int mt = 0; mt < 2; ++mt)
#pragma unroll
                    for (int nt = 0; nt < 4; ++nt)
                        acc[mt][nt] = __builtin_amdgcn_mfma_f32_16x16x32_f16(
                            a[mt], bq[nt], acc[mt][nt], 0, 0, 0);
            }
        }
    }

#pragma unroll
    for (int nt = 0; nt < 4; ++nt) {
        const int oc = nt * 16 + lm;
        const float bias = b1[oc];
#pragma unroll
        for (int mt = 0; mt < 2; ++mt)
#pragma unroll
            for (int r = 0; r < 4; ++r) {
                const int p = wave * 32 + mt * 16 + kg * 4 + r;
                const int y = y0 + (p >> 4), x = x0 + (p & 15);
                feath[(((size_t)b * FH + y + 1) * FW + (x + 1)) * 64 + oc] =
                    f2h(acc[mt][nt][r] + bias);
            }
    }
}

// ---------------------------------------------------------------------------
// Kernel B: offset+mod conv, 16x16 px x 32(27) out per block, f16 MFMA.
// (r8 form, unchanged.)
// ---------------------------------------------------------------------------
__global__ __launch_bounds__(256)
void offmod_mfma_kernel(const u16* __restrict__ feath, const u16* __restrict__ Womt,
                        const float* __restrict__ boff, const float* __restrict__ bmod,
                        float* __restrict__ om)
{
    __shared__ u16 sTile[324 * 36];   // [18x18][c32 pad36] 23.3 KB
    __shared__ u16 sWom[288 * 36];    // [t*32+o][c32 pad36] 20.7 KB

    const int x0 = blockIdx.x * 16;
    const int y0 = blockIdx.y * 16;
    const int b  = blockIdx.z;
    const int tid = threadIdx.x;
    const int lane = tid & 63;
    const int wave = tid >> 6;
    const int lm = lane & 15;
    const int kg = lane >> 4;

    const u16* fb = feath + ((size_t)b * FH * FW) * 64;

    f4v acc[4][2];
#pragma unroll
    for (int i = 0; i < 4; ++i)
#pragma unroll
        for (int j = 0; j < 2; ++j) acc[i][j] = (f4v)0.f;

    for (int chunk = 0; chunk < 2; ++chunk) {
        const int c0 = chunk * 32;
        __syncthreads();
        for (int i = 0; i < 6; ++i) {
            const int idx = tid + 256 * i;
            if (idx < 1296) {
                const int pix = idx >> 2;
                const int q   = idx & 3;
                const int gy = y0 + pix / 18;
                const int gx = x0 + pix % 18;
                *(s8v*)&sTile[pix * 36 + q * 8] =
                    *(const s8v*)(fb + ((size_t)(gy * FW + gx)) * 64 + c0 + q * 8);
            }
        }
        for (int i = 0; i < 5; ++i) {
            const int idx = tid + 256 * i;
            if (idx < 1152) {
                const int row = idx >> 2;     // t*32 + o
                const int q   = idx & 3;
                *(s8v*)&sWom[row * 36 + q * 8] =
                    *(const s8v*)(Womt + (size_t)row * 64 + c0 + q * 8);
            }
        }
        __syncthreads();

#pragma unroll
        for (int t = 0; t < 9; ++t) {
            const int dy = t / 3, dx = t % 3;
            h8 a[4], bq[2];
#pragma unroll
            for (int mt = 0; mt < 4; ++mt) {
                const int p = wave * 64 + mt * 16 + lm;
                const int sidx = ((p >> 4) + dy) * 18 + (p & 15) + dx;
                a[mt] = *(const h8*)&sTile[sidx * 36 + kg * 8];
            }
#pragma unroll
            for (int nt = 0; nt < 2; ++nt) {
                const int o = nt * 16 + lm;
                bq[nt] = *(const h8*)&sWom[(t * 32 + o) * 36 + kg * 8];
            }
#pragma unroll
            for (int mt = 0; mt < 4; ++mt)
#pragma unroll
                for (int nt = 0; nt < 2; ++nt)
                    acc[mt][nt] = __builtin_amdgcn_mfma_f32_16x16x32_f16(
                        a[mt], bq[nt], acc[mt][nt], 0, 0, 0);
        }
    }

#pragma unroll
    for (int nt = 0; nt < 2; ++nt) {
        const int o = nt * 16 + lm;
        if (o >= 27) continue;
#pragma unroll
        for (int mt = 0; mt < 4; ++mt)
#pragma unroll
            for (int r = 0; r < 4; ++r) {
                const int p = wave * 64 + mt * 16 + kg * 4 + r;
                const int y = y0 + (p >> 4), x = x0 + (p & 15);
                float* op = om + (((size_t)b * HH + y) * WW + x) * 27;
                if (o < 18) op[o] = acc[mt][nt][r] + boff[o];
                else {
                    const float z = acc[mt][nt][r] + bmod[o - 18];
                    op[o] = 2.f / (1.f + expf(-z));
                }
            }
    }
}

// ---------------------------------------------------------------------------
// Kernel C: deformable sampling + modulated einsum, f16.
// (r6/r8-proven form: 16x4 px tile, halo records, depth-2 gather pipeline,
// raw barriers, float4 NCHW epilogue.)
// ---------------------------------------------------------------------------
__global__ __launch_bounds__(256, 3)
void dcn_mfma_kernel(const u16* __restrict__ feath, const float* __restrict__ om,
                     const u16* __restrict__ Wdf, const float* __restrict__ bdcn,
                     float* __restrict__ out)
{
    __shared__ u16 sV[2][64 * 72];    // [buf][p][c64 pad72] 2 x 9.2 KB
    __shared__ float sOm[64 * 28];    // [p][27 pad28] 7.2 KB
    __shared__ int sOffs[576 * 4];    // [k*64+p][corner] halo offs 9.2 KB
    __shared__ u16 sWts[576 * 4];     // [k*64+p][corner] f16 w*mod 4.6 KB

    const int b  = blockIdx.z;
    const int x0 = blockIdx.x * 16;
    const int y0 = blockIdx.y * 4;
    const int tid = threadIdx.x;
    const int lane = tid & 63;
    const int wave = tid >> 6;
    const int wi = wave >> 1;
    const int wj = wave & 1;
    const int lm = lane & 15;
    const int kg = lane >> 4;

    for (int idx = tid; idx < 64 * 27; idx += 256) {
        const int p = idx / 27;
        const int j = idx - p * 27;
        const int y = y0 + (p >> 4), x = x0 + (p & 15);
        sOm[p * 28 + j] = om[(((size_t)b * HH + y) * WW + x) * 27 + j];
    }
    __syncthreads();

    // ---- precompute bilinear records (mod folded into corner weights) ----
    for (int idx = tid; idx < 576; idx += 256) {
        const int p = idx & 63, k = idx >> 6;
        const int yy = y0 + (p >> 4), xx = x0 + (p & 15);
        const float dy = sOm[p * 28 + 2 * k];
        const float dx = sOm[p * 28 + 2 * k + 1];
        const float m  = sOm[p * 28 + 18 + k];
        const float pyf = (float)(yy + (k / 3) - 1) + dy;
        const float pxf = (float)(xx + (k % 3) - 1) + dx;
        const float fy0 = floorf(pyf), fx0 = floorf(pxf);
        const float wy1 = pyf - fy0, wx1 = pxf - fx0;
        const int iy0 = (int)fy0, ix0 = (int)fx0;
        const float w[4] = { m * (1.f - wy1) * (1.f - wx1), m * (1.f - wy1) * wx1,
                             m * wy1 * (1.f - wx1),         m * wy1 * wx1 };
        const int ys[4] = { iy0, iy0, iy0 + 1, iy0 + 1 };
        const int xs[4] = { ix0, ix0 + 1, ix0, ix0 + 1 };
#pragma unroll
        for (int cn = 0; cn < 4; ++cn) {
            const bool valid = ((unsigned)ys[cn] < (unsigned)HH) &&
                               ((unsigned)xs[cn] < (unsigned)WW);
            const int hy = min(max(ys[cn], -1), HH);   // [-1,128] -> halo row
            const int hx = min(max(xs[cn], -1), WW);
            sOffs[idx * 4 + cn] = ((hy + 1) * FW + (hx + 1)) * 64;
            sWts[idx * 4 + cn]  = f2h(valid ? w[cn] : 0.f);
        }
    }
    __syncthreads();

    // gather mapping: thread = (pixel p1, 16-ch group)
    const int p1 = tid >> 2;
    const int cb = (tid & 3) * 16;
    const u16* fb  = feath + ((size_t)b * FH * FW) * 64;
    const u16* wfp = Wdf + (size_t)lane * 8;

    f4v acc[2][2];
#pragma unroll
    for (int i = 0; i < 2; ++i)
#pragma unroll
        for (int j = 0; j < 2; ++j) acc[i][j] = (f4v)0.f;

    // depth-2 pipeline registers: two named gather sets (static, rule #20)
    h8 A0, A1, A2, A3, A4, A5, A6, A7; u4v wtA;
    h8 B0, B1, B2, B3, B4, B5, B6, B7; u4v wtB;
    h8 bf[2][2][2];                      // [buf][nt][ks] B-frags

    auto issue = [&](int k, h8& r0, h8& r1, h8& r2, h8& r3,
                     h8& r4, h8& r5, h8& r6, h8& r7, u4v& wt) {
        const int rec = (k * 64 + p1) * 4;
        const int4 o4 = *(const int4*)&sOffs[rec];
        wt = *(const u4v*)&sWts[rec];
        const u16* c0p = fb + o4.x + cb;
        const u16* c1p = fb + o4.y + cb;
        const u16* c2p = fb + o4.z + cb;
        const u16* c3p = fb + o4.w + cb;
        r0 = *(const h8*)(c0p); r1 = *(const h8*)(c0p + 8);
        r2 = *(const h8*)(c1p); r3 = *(const h8*)(c1p + 8);
        r4 = *(const h8*)(c2p); r5 = *(const h8*)(c2p + 8);
        r6 = *(const h8*)(c3p); r7 = *(const h8*)(c3p + 8);
    };

    auto publish = [&](int buf, u4v wt, h8 r0, h8 r1, h8 r2, h8 r3,
                       h8 r4, h8 r5, h8 r6, h8 r7) {
        const h8 w0 = (h8)h_from_bits(wt.x);
        const h8 w1 = (h8)h_from_bits(wt.y);
        const h8 w2 = (h8)h_from_bits(wt.z);
        const h8 w3 = (h8)h_from_bits(wt.w);
        h8 a0 = (h8)(_Float16)0.f, a1 = (h8)(_Float16)0.f;
        a0 += w0 * r0; a1 += w0 * r1;
        a0 += w1 * r2; a1 += w1 * r3;
        a0 += w2 * r4; a1 += w2 * r5;
        a0 += w3 * r6; a1 += w3 * r7;
        *(h8*)&sV[buf][p1 * 72 + cb]     = a0;
        *(h8*)&sV[buf][p1 * 72 + cb + 8] = a1;
    };

    auto loadbf = [&](int k, int buf) {
#pragma unroll
        for (int nt = 0; nt < 2; ++nt)
#pragma unroll
            for (int ks = 0; ks < 2; ++ks)
                bf[buf][nt][ks] = *(const h8*)(wfp +
                    (size_t)((((k * 2 + wj) * 2 + nt) * 2 + ks)) * 512);
    };

    // prologue: g(0)->A, g(1)->B, bf(0), publish(0) from A
    issue(0, A0, A1, A2, A3, A4, A5, A6, A7, wtA);
    issue(1, B0, B1, B2, B3, B4, B5, B6, B7, wtB);
    loadbf(0, 0);
    publish(0, wtA, A0, A1, A2, A3, A4, A5, A6, A7);

#pragma unroll
    for (int k = 0; k < 9; ++k) {
        // issue g(k+2) into the set freed by last iter's publish; no
        // consumption before the barrier -> loads fly across it.
        if (k < 7) {
            if ((k & 1) == 0) issue(k + 2, A0, A1, A2, A3, A4, A5, A6, A7, wtA);
            else              issue(k + 2, B0, B1, B2, B3, B4, B5, B6, B7, wtB);
        }
        if (k < 8) loadbf(k + 1, (k & 1) ^ 1);

        // raw barrier: LDS writes retired (lgkmcnt 0); global loads stay
        // in flight (no vmcnt drain).
        __builtin_amdgcn_sched_barrier(0);
        asm volatile("s_waitcnt lgkmcnt(0)" ::: "memory");
        __builtin_amdgcn_s_barrier();
        __builtin_amdgcn_sched_barrier(0);

        // ---- GEMM: acc += V[64p][64c] * Wd[64c][64oc], tap k ----
        h8 a[2][2];
#pragma unroll
        for (int mt = 0; mt < 2; ++mt) {
            const int p = wi * 32 + mt * 16 + lm;
#pragma unroll
            for (int ks = 0; ks < 2; ++ks)
                a[mt][ks] = *(const h8*)&sV[k & 1][p * 72 + ks * 32 + kg * 8];
        }
#pragma unroll
        for (int mt = 0; mt < 2; ++mt)
#pragma unroll
            for (int nt = 0; nt < 2; ++nt)
#pragma unroll
                for (int ks = 0; ks < 2; ++ks)
                    acc[mt][nt] = __builtin_amdgcn_mfma_f32_16x16x32_f16(
                        a[mt][ks], bf[k & 1][nt][ks], acc[mt][nt], 0, 0, 0);

        // publish(k+1) from the set issued a FULL iteration ago, into the
        // other sV buffer.
        if (k < 8) {
            if ((k & 1) == 0)
                publish(1, wtB, B0, B1, B2, B3, B4, B5, B6, B7);
            else
                publish(0, wtA, A0, A1, A2, A3, A4, A5, A6, A7);
        }
    }

    // epilogue: NCHW fp32, float4 stores (x0..x0+15 covers full 64B lines)
#pragma unroll
    for (int mt = 0; mt < 2; ++mt)
#pragma unroll
        for (int nt = 0; nt < 2; ++nt) {
            const int oc = wj * 32 + nt * 16 + lm;
            const float bias = bdcn[oc];
            const int pbase = wi * 32 + mt * 16 + kg * 4;
            const int y = y0 + (pbase >> 4);
            const int x = x0 + (pbase & 15);
            float4 v;
            v.x = acc[mt][nt][0] + bias;
            v.y = acc[mt][nt][1] + bias;
            v.z = acc[mt][nt][2] + bias;
            v.w = acc[mt][nt][3] + bias;
            *(float4*)&out[(((size_t)b * CC + oc) * HH + y) * WW + x] = v;
        }
}

extern "C" void kernel_launch(void* const* d_in, const int* in_sizes, int n_in,
                              void* d_out, int out_size, void* d_ws, size_t ws_size,
                              hipStream_t stream)
{
    const float* xvq  = (const float*)d_in[0];
    const float* xres = (const float*)d_in[1];
    const float* W1   = (const float*)d_in[2];
    const float* b1   = (const float*)d_in[3];
    const float* Woff = (const float*)d_in[4];
    const float* boff = (const float*)d_in[5];
    const float* Wmod = (const float*)d_in[6];
    const float* bmod = (const float*)d_in[7];
    const float* Wdcn = (const float*)d_in[8];
    const float* bdcn = (const float*)d_in[9];
    float* out = (float*)d_out;

    u16*  feath = (u16*)d_ws;                              // 8.65M u16 (halo)
    float* om   = (float*)(feath + (size_t)BB * FH * FW * 64);  // 3.54M f32
    u16*  xin   = (u16*)(om + (size_t)BB * HH * WW * 27);  // 16.78M u16
    u16*  W1t   = xin + (size_t)BB * HH * WW * 128;        // 73728 u16
    u16*  Womt  = W1t + 9 * 64 * 128;                      // 18432 u16
    u16*  Wdf   = Womt + 9 * 32 * 64;                      // 36864 u16

    prep_kernel<<<dim3(1024 + 633), 256, 0, stream>>>(
        xvq, xres, xin, W1, Woff, Wmod, Wdcn, W1t, Womt, Wdf, feath);
    conv1_mfma_kernel<<<dim3(8, 16, 8), 256, 0, stream>>>(xin, W1t, b1, feath);
    offmod_mfma_kernel<<<dim3(8, 8, 8), 256, 0, stream>>>(feath, Womt, boff, bmod, om);
    dcn_mfma_kernel<<<dim3(8, 32, 8), 256, 0, stream>>>(feath, om, Wdf, bdcn, out);
}